// Round 4
// baseline (450.862 us; speedup 1.0000x reference)
//
#include <hip/hip_runtime.h>
#include <math.h>

#define NN 50000
#define NE 800000
#define DD 128

__device__ __forceinline__ int clampN(int v) {
  return v < 0 ? 0 : (v >= NN ? NN - 1 : v);
}

// ---------------- CSR build ----------------

__global__ void k_zero(int* __restrict__ deg, int* __restrict__ cur, int n) {
  int i = blockIdx.x * blockDim.x + threadIdx.x;
  if (i < n) { deg[i] = 0; cur[i] = 0; }
}

__global__ void k_count(const int* __restrict__ dst, int* __restrict__ deg, int e) {
  int i = blockIdx.x * blockDim.x + threadIdx.x;
  if (i < e) atomicAdd(&deg[clampN(dst[i])], 1);
}

__global__ void k_dinv(const int* __restrict__ deg, float* __restrict__ dinv, int n) {
  int i = blockIdx.x * blockDim.x + threadIdx.x;
  if (i < n) dinv[i] = rsqrtf(1.0f + (float)deg[i]);  // +1 for self-loop
}

__global__ void k_scan1(const int* __restrict__ deg, int* __restrict__ rp,
                        int* __restrict__ bsums, int n) {
  __shared__ int sh[256];
  int i = blockIdx.x * 256 + threadIdx.x;
  int v = (i < n) ? deg[i] : 0;
  sh[threadIdx.x] = v;
  __syncthreads();
  for (int off = 1; off < 256; off <<= 1) {
    int t = (threadIdx.x >= off) ? sh[threadIdx.x - off] : 0;
    __syncthreads();
    sh[threadIdx.x] += t;
    __syncthreads();
  }
  if (i < n) rp[i] = sh[threadIdx.x] - v;          // exclusive
  if (threadIdx.x == 255) bsums[blockIdx.x] = sh[255];
}

__global__ void k_scan2(int* __restrict__ bsums, int nb) {
  __shared__ int sh[256];
  int v = (threadIdx.x < nb) ? bsums[threadIdx.x] : 0;
  sh[threadIdx.x] = v;
  __syncthreads();
  for (int off = 1; off < 256; off <<= 1) {
    int t = (threadIdx.x >= off) ? sh[threadIdx.x - off] : 0;
    __syncthreads();
    sh[threadIdx.x] += t;
    __syncthreads();
  }
  if (threadIdx.x < nb) bsums[threadIdx.x] = sh[threadIdx.x] - v;  // exclusive
}

__global__ void k_scan3(int* __restrict__ rp, const int* __restrict__ bsums, int n, int e) {
  int i = blockIdx.x * blockDim.x + threadIdx.x;
  if (i < n) rp[i] += bsums[i >> 8];
  if (i == 0) rp[n] = e;
}

__global__ void k_scatter(const int* __restrict__ ei, const int* __restrict__ rp,
                          int* __restrict__ cur, int* __restrict__ col, int e) {
  int i = blockIdx.x * blockDim.x + threadIdx.x;
  if (i < e) {
    int s = clampN(ei[i]);
    int d = clampN(ei[NE + i]);
    int pos = rp[d] + atomicAdd(&cur[d], 1);
    col[pos] = s;   // pos < NE by construction (sum of deg == NE)
  }
}

// ---------------- GEMM: out[i,c] = dinv[i] * sum_k in[i,k]*W[k,c] ----------------
// 16 rows per block, 256 threads: col = tid&127, row-half = tid>>7 (8 rows each).

__global__ __launch_bounds__(256) void k_gemm_scale(
    const float* __restrict__ in, const float* __restrict__ W,
    const float* __restrict__ dinv, float* __restrict__ out) {
  __shared__ float Wl[DD * DD];  // 64 KB
  for (int idx = threadIdx.x; idx < DD * DD / 4; idx += 256) {
    ((float4*)Wl)[idx] = ((const float4*)W)[idx];
  }
  __syncthreads();

  int col = threadIdx.x & 127;
  int half = threadIdx.x >> 7;
  int row0 = blockIdx.x * 16 + half * 8;

  float acc[8] = {0.f, 0.f, 0.f, 0.f, 0.f, 0.f, 0.f, 0.f};
  for (int k = 0; k < DD; k += 4) {
    float w0 = Wl[(k + 0) * DD + col];
    float w1 = Wl[(k + 1) * DD + col];
    float w2 = Wl[(k + 2) * DD + col];
    float w3 = Wl[(k + 3) * DD + col];
#pragma unroll
    for (int r = 0; r < 8; ++r) {
      float4 xv = *(const float4*)&in[(row0 + r) * DD + k];
      acc[r] += xv.x * w0 + xv.y * w1 + xv.z * w2 + xv.w * w3;
    }
  }
#pragma unroll
  for (int r = 0; r < 8; ++r) {
    int row = row0 + r;
    out[row * DD + col] = acc[r] * dinv[row];
  }
}

// ---------------- Aggregate: acc[d] = tp[d] + sum_{s in in(d)} tp[s] ----------------
// One wave per node; lane holds cols {2*lane, 2*lane+1}. 4 nodes per 256-block.

__global__ __launch_bounds__(256) void k_aggregate_relu(
    const float* __restrict__ tp, const float* __restrict__ dinv,
    const float* __restrict__ b, const int* __restrict__ rp,
    const int* __restrict__ col, float* __restrict__ out) {
  int wid = threadIdx.x >> 6;
  int lane = threadIdx.x & 63;
  int d = blockIdx.x * 4 + wid;
  int c0 = lane * 2;

  float2 acc = *(const float2*)(tp + d * DD + c0);  // self loop
  int start = rp[d], end = rp[d + 1];
  for (int base = start; base < end; base += 64) {
    int idx = 0;
    if (base + lane < end) idx = col[base + lane];
    int cnt = min(64, end - base);
    for (int i = 0; i < cnt; ++i) {
      int s = __shfl(idx, i, 64);
      float2 v = *(const float2*)(tp + s * DD + c0);
      acc.x += v.x;
      acc.y += v.y;
    }
  }
  float dv = dinv[d];
  float2 bb = *(const float2*)(b + c0);
  float o0 = fmaxf(dv * acc.x + bb.x, 0.f);
  float o1 = fmaxf(dv * acc.y + bb.y, 0.f);
  *(float2*)(out + d * DD + c0) = make_float2(o0, o1);
}

__global__ __launch_bounds__(256) void k_aggregate_head(
    const float* __restrict__ tp, const float* __restrict__ dinv,
    const float* __restrict__ b, const float* __restrict__ Wl,
    const float* __restrict__ bl, const int* __restrict__ rp,
    const int* __restrict__ col, float* __restrict__ out) {
  int wid = threadIdx.x >> 6;
  int lane = threadIdx.x & 63;
  int d = blockIdx.x * 4 + wid;
  int c0 = lane * 2;

  float2 acc = *(const float2*)(tp + d * DD + c0);  // self loop
  int start = rp[d], end = rp[d + 1];
  for (int base = start; base < end; base += 64) {
    int idx = 0;
    if (base + lane < end) idx = col[base + lane];
    int cnt = min(64, end - base);
    for (int i = 0; i < cnt; ++i) {
      int s = __shfl(idx, i, 64);
      float2 v = *(const float2*)(tp + s * DD + c0);
      acc.x += v.x;
      acc.y += v.y;
    }
  }
  float dv = dinv[d];
  float h0 = dv * acc.x + b[c0];
  float h1 = dv * acc.y + b[c0 + 1];
  float partial = h0 * Wl[c0] + h1 * Wl[c0 + 1];
#pragma unroll
  for (int off = 32; off > 0; off >>= 1) partial += __shfl_down(partial, off, 64);
  if (lane == 0) out[d] = 1.f / (1.f + expf(-(partial + bl[0])));
}

// ---------------- launch ----------------

extern "C" void kernel_launch(void* const* d_in, const int* in_sizes, int n_in,
                              void* d_out, int out_size, void* d_ws, size_t ws_size,
                              hipStream_t stream) {
  const float* x = (const float*)d_in[0];
  const int* ei = (const int*)d_in[1];   // harness passes integer inputs as int32
  const float* W1 = (const float*)d_in[2];
  const float* b1 = (const float*)d_in[3];
  const float* W2 = (const float*)d_in[4];
  const float* b2 = (const float*)d_in[5];
  const float* Wl = (const float*)d_in[6];
  const float* bl = (const float*)d_in[7];
  float* out = (float*)d_out;

  // workspace carve-up (256B aligned)
  char* ws = (char*)d_ws;
  size_t off = 0;
  auto alloc = [&](size_t bytes) -> char* {
    char* p = ws + off;
    off = (off + bytes + 255) & ~(size_t)255;
    return p;
  };
  int* deg = (int*)alloc(NN * sizeof(int));
  int* cur = (int*)alloc(NN * sizeof(int));
  float* dinv = (float*)alloc(NN * sizeof(float));
  int* rp = (int*)alloc((NN + 1) * sizeof(int));
  int* bsums = (int*)alloc(256 * sizeof(int));
  int* colidx = (int*)alloc(NE * sizeof(int));
  float* tp = (float*)alloc((size_t)NN * DD * sizeof(float));
  float* h1 = (float*)alloc((size_t)NN * DD * sizeof(float));
  (void)ws_size;

  const int NB_N = (NN + 255) / 256;   // 196
  const int NB_E = (NE + 255) / 256;   // 3125
  const int* dst = ei + NE;

  k_zero<<<NB_N, 256, 0, stream>>>(deg, cur, NN);
  k_count<<<NB_E, 256, 0, stream>>>(dst, deg, NE);
  k_dinv<<<NB_N, 256, 0, stream>>>(deg, dinv, NN);
  k_scan1<<<NB_N, 256, 0, stream>>>(deg, rp, bsums, NN);
  k_scan2<<<1, 256, 0, stream>>>(bsums, NB_N);
  k_scan3<<<NB_N, 256, 0, stream>>>(rp, bsums, NN, NE);
  k_scatter<<<NB_E, 256, 0, stream>>>(ei, rp, cur, colidx, NE);

  // layer 1
  k_gemm_scale<<<NN / 16, 256, 0, stream>>>(x, W1, dinv, tp);
  k_aggregate_relu<<<NN / 4, 256, 0, stream>>>(tp, dinv, b1, rp, colidx, h1);
  // layer 2 + head
  k_gemm_scale<<<NN / 16, 256, 0, stream>>>(h1, W2, dinv, tp);
  k_aggregate_head<<<NN / 4, 256, 0, stream>>>(tp, dinv, b2, Wl, bl, rp, colidx, out);
}

// Round 5
// 243.211 us; speedup vs baseline: 1.8538x; 1.8538x over previous
//
#include <hip/hip_runtime.h>
#include <math.h>

#define NN 50000
#define NE 800000
#define DD 128
#define NPAD 50048   // 782 * 64, GEMM row padding

typedef __attribute__((ext_vector_type(8))) short bf16x8;
typedef __attribute__((ext_vector_type(4))) float f32x4;

__device__ __forceinline__ int clampN(int v) {
  return v < 0 ? 0 : (v >= NN ? NN - 1 : v);
}

__device__ __forceinline__ unsigned short f2b(float f) {
  union { float f; unsigned int u; } x; x.f = f;
  unsigned int u = x.u;
  u += 0x7fffu + ((u >> 16) & 1u);   // round-to-nearest-even
  return (unsigned short)(u >> 16);
}

__device__ __forceinline__ float2 b2f2(unsigned int v) {
  union { unsigned int u; float f; } a, b;
  a.u = v << 16;            // low ushort = even col
  b.u = v & 0xffff0000u;    // high ushort = odd col
  return make_float2(a.f, b.f);
}

// ---------------- CSR build ----------------

__global__ void k_zero(int* __restrict__ deg, int* __restrict__ cur, int n) {
  int i = blockIdx.x * blockDim.x + threadIdx.x;
  if (i < n) { deg[i] = 0; cur[i] = 0; }
}

__global__ void k_count(const int* __restrict__ dst, int* __restrict__ deg, int e) {
  int i = blockIdx.x * blockDim.x + threadIdx.x;
  if (i < e) atomicAdd(&deg[clampN(dst[i])], 1);
}

__global__ void k_dinv(const int* __restrict__ deg, float* __restrict__ dinv, int n) {
  int i = blockIdx.x * blockDim.x + threadIdx.x;
  if (i < n) dinv[i] = rsqrtf(1.0f + (float)deg[i]);  // +1 for self-loop
}

__global__ void k_scan1(const int* __restrict__ deg, int* __restrict__ rp,
                        int* __restrict__ bsums, int n) {
  __shared__ int sh[256];
  int i = blockIdx.x * 256 + threadIdx.x;
  int v = (i < n) ? deg[i] : 0;
  sh[threadIdx.x] = v;
  __syncthreads();
  for (int off = 1; off < 256; off <<= 1) {
    int t = (threadIdx.x >= off) ? sh[threadIdx.x - off] : 0;
    __syncthreads();
    sh[threadIdx.x] += t;
    __syncthreads();
  }
  if (i < n) rp[i] = sh[threadIdx.x] - v;          // exclusive
  if (threadIdx.x == 255) bsums[blockIdx.x] = sh[255];
}

__global__ void k_scan2(int* __restrict__ bsums, int nb) {
  __shared__ int sh[256];
  int v = (threadIdx.x < nb) ? bsums[threadIdx.x] : 0;
  sh[threadIdx.x] = v;
  __syncthreads();
  for (int off = 1; off < 256; off <<= 1) {
    int t = (threadIdx.x >= off) ? sh[threadIdx.x - off] : 0;
    __syncthreads();
    sh[threadIdx.x] += t;
    __syncthreads();
  }
  if (threadIdx.x < nb) bsums[threadIdx.x] = sh[threadIdx.x] - v;  // exclusive
}

__global__ void k_scan3(int* __restrict__ rp, const int* __restrict__ bsums, int n, int e) {
  int i = blockIdx.x * blockDim.x + threadIdx.x;
  if (i < n) rp[i] += bsums[i >> 8];
  if (i == 0) rp[n] = e;
}

__global__ void k_scatter(const int* __restrict__ ei, const int* __restrict__ rp,
                          int* __restrict__ cur, int* __restrict__ col, int e) {
  int i = blockIdx.x * blockDim.x + threadIdx.x;
  if (i < e) {
    int s = clampN(ei[i]);
    int d = clampN(ei[NE + i]);
    int pos = rp[d] + atomicAdd(&cur[d], 1);
    col[pos] = s;
  }
}

// ---------------- prep: X -> bf16 (padded), W -> W^T bf16 ----------------

__global__ void k_xb(const float* __restrict__ x, ushort4* __restrict__ Xb) {
  int i = blockIdx.x * blockDim.x + threadIdx.x;  // one per 4 elements
  if (i >= NPAD * (DD / 4)) return;
  int row = i / (DD / 4);
  ushort4 o;
  if (row < NN) {
    float4 v = ((const float4*)x)[i];
    o.x = f2b(v.x); o.y = f2b(v.y); o.z = f2b(v.z); o.w = f2b(v.w);
  } else {
    o.x = o.y = o.z = o.w = 0;
  }
  Xb[i] = o;
}

__global__ void k_wt(const float* __restrict__ W1, const float* __restrict__ W2,
                     unsigned short* __restrict__ Wt1, unsigned short* __restrict__ Wt2) {
  int i = blockIdx.x * blockDim.x + threadIdx.x;
  if (i < DD * DD) {
    int n = i >> 7, k = i & 127;
    Wt1[i] = f2b(W1[k * DD + n]);
  } else if (i < 2 * DD * DD) {
    int j = i - DD * DD;
    int n = j >> 7, k = j & 127;
    Wt2[j] = f2b(W2[k * DD + n]);
  }
}

// ---------------- MFMA GEMM: outb[r,c] = bf16( dinv[r] * sum_k A[r,k]*W[k,c] ) ----
// A: [NPAD][128] bf16 row-major. Wt: [128][128] bf16, Wt[n][k] = W[k][n].
// 64 rows/block, 256 threads = 4 waves, wave w owns rows [w*16, w*16+16).
// LDS XOR-swizzle (byte ^= (row&7)<<4) keeps stride-256B fragment reads conflict-free.

__global__ __launch_bounds__(256) void k_gemm_mfma(
    const unsigned short* __restrict__ Ab, const unsigned short* __restrict__ Wt,
    const float* __restrict__ dinv, unsigned short* __restrict__ outb) {
  __shared__ char lds[16384 + 32768];
  char* Al = lds;            // 64 rows x 256 B
  char* Wl = lds + 16384;    // 128 rows x 256 B

  const int tid = threadIdx.x;
  const int row0 = blockIdx.x * 64;

  {  // stage A tile (16 KB), swizzled
    const uint4* src = (const uint4*)(Ab + (size_t)row0 * DD);
    for (int idx = tid; idx < 1024; idx += 256) {
      int bo = idx * 16;
      int r = bo >> 8;
      *(uint4*)(Al + (bo ^ ((r & 7) << 4))) = src[idx];
    }
  }
  {  // stage Wt (32 KB), swizzled
    const uint4* src = (const uint4*)Wt;
    for (int idx = tid; idx < 2048; idx += 256) {
      int bo = idx * 16;
      int r = bo >> 8;
      *(uint4*)(Wl + (bo ^ ((r & 7) << 4))) = src[idx];
    }
  }
  __syncthreads();

  const int w = tid >> 6, lane = tid & 63;
  const int lr = lane & 15, lk = lane >> 4;

  bf16x8 af[4];
  {
    int ar = w * 16 + lr;
    int base = ar * 256 + lk * 16;
    int swz = (ar & 7) << 4;
#pragma unroll
    for (int k4 = 0; k4 < 4; ++k4)
      af[k4] = *(const bf16x8*)(Al + ((base + k4 * 64) ^ swz));
  }

  f32x4 accs[8];
#pragma unroll
  for (int n = 0; n < 8; ++n) {
    f32x4 acc = {0.f, 0.f, 0.f, 0.f};
    int br = n * 16 + lr;
    int bbase = br * 256 + lk * 16;
    int bswz = (br & 7) << 4;
#pragma unroll
    for (int k4 = 0; k4 < 4; ++k4) {
      bf16x8 bf = *(const bf16x8*)(Wl + ((bbase + k4 * 64) ^ bswz));
      acc = __builtin_amdgcn_mfma_f32_16x16x32_bf16(af[k4], bf, acc, 0, 0, 0);
    }
    accs[n] = acc;
  }

#pragma unroll
  for (int r = 0; r < 4; ++r) {
    int grow = row0 + w * 16 + lk * 4 + r;
    if (grow < NN) {
      float dv = dinv[grow];
#pragma unroll
      for (int n = 0; n < 8; ++n)
        outb[(size_t)grow * DD + n * 16 + lr] = f2b(accs[n][r] * dv);
    }
  }
}

// ---------------- Aggregate over bf16 tp, fp32 accumulate ----------------
// One wave per node; lane holds cols {2*lane, 2*lane+1} (one uint = 2 bf16).

__global__ __launch_bounds__(256) void k_agg_relu_b(
    const unsigned int* __restrict__ tpb, const float* __restrict__ dinv,
    const float* __restrict__ b, const int* __restrict__ rp,
    const int* __restrict__ col, unsigned int* __restrict__ outb) {
  int wid = threadIdx.x >> 6;
  int lane = threadIdx.x & 63;
  int d = blockIdx.x * 4 + wid;
  int c0 = lane * 2;

  float2 acc = b2f2(tpb[(size_t)d * 64 + lane]);  // self loop
  int start = rp[d], end = rp[d + 1];
  for (int base = start; base < end; base += 64) {
    int idx = 0;
    if (base + lane < end) idx = col[base + lane];
    int cnt = min(64, end - base);
    for (int i = 0; i < cnt; ++i) {
      int s = __shfl(idx, i, 64);
      float2 v = b2f2(tpb[(size_t)s * 64 + lane]);
      acc.x += v.x;
      acc.y += v.y;
    }
  }
  float dv = dinv[d];
  float o0 = fmaxf(dv * acc.x + b[c0], 0.f);
  float o1 = fmaxf(dv * acc.y + b[c0 + 1], 0.f);
  outb[(size_t)d * 64 + lane] = (unsigned int)f2b(o0) | ((unsigned int)f2b(o1) << 16);
}

__global__ __launch_bounds__(256) void k_agg_head_b(
    const unsigned int* __restrict__ tpb, const float* __restrict__ dinv,
    const float* __restrict__ b, const float* __restrict__ Wl,
    const float* __restrict__ bl, const int* __restrict__ rp,
    const int* __restrict__ col, float* __restrict__ out) {
  int wid = threadIdx.x >> 6;
  int lane = threadIdx.x & 63;
  int d = blockIdx.x * 4 + wid;
  int c0 = lane * 2;

  float2 acc = b2f2(tpb[(size_t)d * 64 + lane]);  // self loop
  int start = rp[d], end = rp[d + 1];
  for (int base = start; base < end; base += 64) {
    int idx = 0;
    if (base + lane < end) idx = col[base + lane];
    int cnt = min(64, end - base);
    for (int i = 0; i < cnt; ++i) {
      int s = __shfl(idx, i, 64);
      float2 v = b2f2(tpb[(size_t)s * 64 + lane]);
      acc.x += v.x;
      acc.y += v.y;
    }
  }
  float dv = dinv[d];
  float h0 = dv * acc.x + b[c0];
  float h1 = dv * acc.y + b[c0 + 1];
  float partial = h0 * Wl[c0] + h1 * Wl[c0 + 1];
#pragma unroll
  for (int off = 32; off > 0; off >>= 1) partial += __shfl_down(partial, off, 64);
  if (lane == 0) out[d] = 1.f / (1.f + expf(-(partial + bl[0])));
}

// ---------------- launch ----------------

extern "C" void kernel_launch(void* const* d_in, const int* in_sizes, int n_in,
                              void* d_out, int out_size, void* d_ws, size_t ws_size,
                              hipStream_t stream) {
  const float* x = (const float*)d_in[0];
  const int* ei = (const int*)d_in[1];   // harness passes integer inputs as int32
  const float* W1 = (const float*)d_in[2];
  const float* b1 = (const float*)d_in[3];
  const float* W2 = (const float*)d_in[4];
  const float* b2 = (const float*)d_in[5];
  const float* Wl = (const float*)d_in[6];
  const float* bl = (const float*)d_in[7];
  float* out = (float*)d_out;

  char* ws = (char*)d_ws;
  size_t off = 0;
  auto alloc = [&](size_t bytes) -> char* {
    char* p = ws + off;
    off = (off + bytes + 255) & ~(size_t)255;
    return p;
  };
  int* deg = (int*)alloc(NN * sizeof(int));
  int* cur = (int*)alloc(NN * sizeof(int));
  float* dinv = (float*)alloc(NN * sizeof(float));
  int* rp = (int*)alloc((NN + 1) * sizeof(int));
  int* bsums = (int*)alloc(256 * sizeof(int));
  int* colidx = (int*)alloc(NE * sizeof(int));
  unsigned short* Xb = (unsigned short*)alloc((size_t)NPAD * DD * 2);
  unsigned short* Wt1 = (unsigned short*)alloc(DD * DD * 2);
  unsigned short* Wt2 = (unsigned short*)alloc(DD * DD * 2);
  unsigned short* tpb = (unsigned short*)alloc((size_t)NPAD * DD * 2);
  unsigned short* h1b = (unsigned short*)alloc((size_t)NPAD * DD * 2);
  (void)ws_size;

  const int NB_N = (NN + 255) / 256;   // 196
  const int NB_E = (NE + 255) / 256;   // 3125
  const int* dst = ei + NE;

  k_zero<<<NB_N, 256, 0, stream>>>(deg, cur, NN);
  k_count<<<NB_E, 256, 0, stream>>>(dst, deg, NE);
  k_dinv<<<NB_N, 256, 0, stream>>>(deg, dinv, NN);
  k_scan1<<<NB_N, 256, 0, stream>>>(deg, rp, bsums, NN);
  k_scan2<<<1, 256, 0, stream>>>(bsums, NB_N);
  k_scan3<<<NB_N, 256, 0, stream>>>(rp, bsums, NN, NE);
  k_scatter<<<NB_E, 256, 0, stream>>>(ei, rp, cur, colidx, NE);

  // prep bf16 operands
  k_xb<<<(NPAD * (DD / 4) + 255) / 256, 256, 0, stream>>>(x, (ushort4*)Xb);
  k_wt<<<(2 * DD * DD + 255) / 256, 256, 0, stream>>>(W1, W2, Wt1, Wt2);

  // layer 1
  k_gemm_mfma<<<NPAD / 64, 256, 0, stream>>>(Xb, Wt1, dinv, tpb);
  k_agg_relu_b<<<NN / 4, 256, 0, stream>>>((const unsigned int*)tpb, dinv, b1, rp,
                                           colidx, (unsigned int*)h1b);
  // layer 2 + head
  k_gemm_mfma<<<NPAD / 64, 256, 0, stream>>>(h1b, Wt2, dinv, tpb);
  k_agg_head_b<<<NN / 4, 256, 0, stream>>>((const unsigned int*)tpb, dinv, b2, Wl, bl,
                                           rp, colidx, out);
}

// Round 6
// 201.714 us; speedup vs baseline: 2.2352x; 1.2057x over previous
//
#include <hip/hip_runtime.h>
#include <math.h>

#define NN 50000
#define NE 800000
#define DD 128
#define NPAD 50048   // 782 * 64, GEMM row padding

typedef __attribute__((ext_vector_type(8))) short bf16x8;
typedef __attribute__((ext_vector_type(4))) float f32x4;

__device__ __forceinline__ int clampN(int v) {
  return v < 0 ? 0 : (v >= NN ? NN - 1 : v);
}

__device__ __forceinline__ unsigned short f2b(float f) {
  union { float f; unsigned int u; } x; x.f = f;
  unsigned int u = x.u;
  u += 0x7fffu + ((u >> 16) & 1u);   // round-to-nearest-even
  return (unsigned short)(u >> 16);
}

__device__ __forceinline__ float blo(unsigned int v) {
  union { unsigned int u; float f; } a; a.u = v << 16; return a.f;
}
__device__ __forceinline__ float bhi(unsigned int v) {
  union { unsigned int u; float f; } a; a.u = v & 0xffff0000u; return a.f;
}

// ---------------- CSR build ----------------

__global__ void k_zero(int* __restrict__ deg, int* __restrict__ cur, int n) {
  int i = blockIdx.x * blockDim.x + threadIdx.x;
  if (i < n) { deg[i] = 0; cur[i] = 0; }
}

__global__ void k_count(const int* __restrict__ dst, int* __restrict__ deg, int e) {
  int i = blockIdx.x * blockDim.x + threadIdx.x;
  if (i < e) atomicAdd(&deg[clampN(dst[i])], 1);
}

__global__ void k_dinv(const int* __restrict__ deg, float* __restrict__ dinv, int n) {
  int i = blockIdx.x * blockDim.x + threadIdx.x;
  if (i < n) dinv[i] = rsqrtf(1.0f + (float)deg[i]);  // +1 for self-loop
}

__global__ void k_scan1(const int* __restrict__ deg, int* __restrict__ rp,
                        int* __restrict__ bsums, int n) {
  __shared__ int sh[256];
  int i = blockIdx.x * 256 + threadIdx.x;
  int v = (i < n) ? deg[i] : 0;
  sh[threadIdx.x] = v;
  __syncthreads();
  for (int off = 1; off < 256; off <<= 1) {
    int t = (threadIdx.x >= off) ? sh[threadIdx.x - off] : 0;
    __syncthreads();
    sh[threadIdx.x] += t;
    __syncthreads();
  }
  if (i < n) rp[i] = sh[threadIdx.x] - v;          // exclusive
  if (threadIdx.x == 255) bsums[blockIdx.x] = sh[255];
}

__global__ void k_scan2(int* __restrict__ bsums, int nb) {
  __shared__ int sh[256];
  int v = (threadIdx.x < nb) ? bsums[threadIdx.x] : 0;
  sh[threadIdx.x] = v;
  __syncthreads();
  for (int off = 1; off < 256; off <<= 1) {
    int t = (threadIdx.x >= off) ? sh[threadIdx.x - off] : 0;
    __syncthreads();
    sh[threadIdx.x] += t;
    __syncthreads();
  }
  if (threadIdx.x < nb) bsums[threadIdx.x] = sh[threadIdx.x] - v;  // exclusive
}

__global__ void k_scan3(int* __restrict__ rp, const int* __restrict__ bsums, int n, int e) {
  int i = blockIdx.x * blockDim.x + threadIdx.x;
  if (i < n) rp[i] += bsums[i >> 8];
  if (i == 0) rp[n] = e;
}

__global__ void k_scatter(const int* __restrict__ ei, const int* __restrict__ rp,
                          int* __restrict__ cur, int* __restrict__ col, int e) {
  int i = blockIdx.x * blockDim.x + threadIdx.x;
  if (i < e) {
    int s = clampN(ei[i]);
    int d = clampN(ei[NE + i]);
    int pos = rp[d] + atomicAdd(&cur[d], 1);
    col[pos] = s;
  }
}

// ---------------- prep: X -> bf16 (padded), W -> W^T bf16 ----------------

__global__ void k_xb(const float* __restrict__ x, ushort4* __restrict__ Xb) {
  int i = blockIdx.x * blockDim.x + threadIdx.x;  // one per 4 elements
  if (i >= NPAD * (DD / 4)) return;
  int row = i / (DD / 4);
  ushort4 o;
  if (row < NN) {
    float4 v = ((const float4*)x)[i];
    o.x = f2b(v.x); o.y = f2b(v.y); o.z = f2b(v.z); o.w = f2b(v.w);
  } else {
    o.x = o.y = o.z = o.w = 0;
  }
  Xb[i] = o;
}

__global__ void k_wt(const float* __restrict__ W1, const float* __restrict__ W2,
                     unsigned short* __restrict__ Wt1, unsigned short* __restrict__ Wt2) {
  int i = blockIdx.x * blockDim.x + threadIdx.x;
  if (i < DD * DD) {
    int n = i >> 7, k = i & 127;
    Wt1[i] = f2b(W1[k * DD + n]);
  } else if (i < 2 * DD * DD) {
    int j = i - DD * DD;
    int n = j >> 7, k = j & 127;
    Wt2[j] = f2b(W2[k * DD + n]);
  }
}

// ---------------- MFMA GEMM (unchanged from round 5) ----------------

__global__ __launch_bounds__(256) void k_gemm_mfma(
    const unsigned short* __restrict__ Ab, const unsigned short* __restrict__ Wt,
    const float* __restrict__ dinv, unsigned short* __restrict__ outb) {
  __shared__ char lds[16384 + 32768];
  char* Al = lds;            // 64 rows x 256 B
  char* Wl = lds + 16384;    // 128 rows x 256 B

  const int tid = threadIdx.x;
  const int row0 = blockIdx.x * 64;

  {  // stage A tile (16 KB), swizzled
    const uint4* src = (const uint4*)(Ab + (size_t)row0 * DD);
    for (int idx = tid; idx < 1024; idx += 256) {
      int bo = idx * 16;
      int r = bo >> 8;
      *(uint4*)(Al + (bo ^ ((r & 7) << 4))) = src[idx];
    }
  }
  {  // stage Wt (32 KB), swizzled
    const uint4* src = (const uint4*)Wt;
    for (int idx = tid; idx < 2048; idx += 256) {
      int bo = idx * 16;
      int r = bo >> 8;
      *(uint4*)(Wl + (bo ^ ((r & 7) << 4))) = src[idx];
    }
  }
  __syncthreads();

  const int w = tid >> 6, lane = tid & 63;
  const int lr = lane & 15, lk = lane >> 4;

  bf16x8 af[4];
  {
    int ar = w * 16 + lr;
    int base = ar * 256 + lk * 16;
    int swz = (ar & 7) << 4;
#pragma unroll
    for (int k4 = 0; k4 < 4; ++k4)
      af[k4] = *(const bf16x8*)(Al + ((base + k4 * 64) ^ swz));
  }

  f32x4 accs[8];
#pragma unroll
  for (int n = 0; n < 8; ++n) {
    f32x4 acc = {0.f, 0.f, 0.f, 0.f};
    int br = n * 16 + lr;
    int bbase = br * 256 + lk * 16;
    int bswz = (br & 7) << 4;
#pragma unroll
    for (int k4 = 0; k4 < 4; ++k4) {
      bf16x8 bf = *(const bf16x8*)(Wl + ((bbase + k4 * 64) ^ bswz));
      acc = __builtin_amdgcn_mfma_f32_16x16x32_bf16(af[k4], bf, acc, 0, 0, 0);
    }
    accs[n] = acc;
  }

#pragma unroll
  for (int r = 0; r < 4; ++r) {
    int grow = row0 + w * 16 + lk * 4 + r;
    if (grow < NN) {
      float dv = dinv[grow];
#pragma unroll
      for (int n = 0; n < 8; ++n)
        outb[(size_t)grow * DD + n * 16 + lr] = f2b(accs[n][r] * dv);
    }
  }
}

// ---------------- Aggregate v2: 4 edges in flight per wave ----------------
// Wave = 4 groups x 16 lanes. Group g handles edge (base+it+g); lane il=lane&15
// loads 16 B (8 bf16 cols il*8..il*8+7). Cross-group combine: shfl_xor 16,32.

__device__ __forceinline__ void acc8(float* acc, uint4 v, float m) {
  acc[0] = fmaf(m, blo(v.x), acc[0]);
  acc[1] = fmaf(m, bhi(v.x), acc[1]);
  acc[2] = fmaf(m, blo(v.y), acc[2]);
  acc[3] = fmaf(m, bhi(v.y), acc[3]);
  acc[4] = fmaf(m, blo(v.z), acc[4]);
  acc[5] = fmaf(m, bhi(v.z), acc[5]);
  acc[6] = fmaf(m, blo(v.w), acc[6]);
  acc[7] = fmaf(m, bhi(v.w), acc[7]);
}

__global__ __launch_bounds__(256) void k_agg_relu_b2(
    const uint4* __restrict__ tpb4, const float* __restrict__ dinv,
    const float* __restrict__ b, const int* __restrict__ rp,
    const int* __restrict__ col, uint4* __restrict__ outb4) {
  int wid = threadIdx.x >> 6;
  int lane = threadIdx.x & 63;
  int d = blockIdx.x * 4 + wid;
  int il = lane & 15, g = lane >> 4;

  float acc[8] = {0.f, 0.f, 0.f, 0.f, 0.f, 0.f, 0.f, 0.f};
  int start = rp[d], end = rp[d + 1];
  for (int base = start; base < end; base += 64) {
    int idx = (base + lane < end) ? col[base + lane] : 0;
    int cnt = min(64, end - base);
    for (int it = 0; it < cnt; it += 4) {
      int e = it + g;
      int s = __shfl(idx, e, 64);        // e<64; invalid lanes hold idx=0 (safe row)
      uint4 v = tpb4[(size_t)s * 16 + il];
      acc8(acc, v, (e < cnt) ? 1.f : 0.f);
    }
  }
#pragma unroll
  for (int j = 0; j < 8; ++j) {
    acc[j] += __shfl_xor(acc[j], 16, 64);
    acc[j] += __shfl_xor(acc[j], 32, 64);
  }
  // self loop (all lanes compute; group 0 stores)
  uint4 sv = tpb4[(size_t)d * 16 + il];
  acc8(acc, sv, 1.f);

  float dv = dinv[d];
  float4 b0 = ((const float4*)b)[il * 2];
  float4 b1 = ((const float4*)b)[il * 2 + 1];
  float o[8];
  o[0] = fmaxf(fmaf(dv, acc[0], b0.x), 0.f);
  o[1] = fmaxf(fmaf(dv, acc[1], b0.y), 0.f);
  o[2] = fmaxf(fmaf(dv, acc[2], b0.z), 0.f);
  o[3] = fmaxf(fmaf(dv, acc[3], b0.w), 0.f);
  o[4] = fmaxf(fmaf(dv, acc[4], b1.x), 0.f);
  o[5] = fmaxf(fmaf(dv, acc[5], b1.y), 0.f);
  o[6] = fmaxf(fmaf(dv, acc[6], b1.z), 0.f);
  o[7] = fmaxf(fmaf(dv, acc[7], b1.w), 0.f);
  if (g == 0) {
    uint4 ov;
    ov.x = (unsigned int)f2b(o[0]) | ((unsigned int)f2b(o[1]) << 16);
    ov.y = (unsigned int)f2b(o[2]) | ((unsigned int)f2b(o[3]) << 16);
    ov.z = (unsigned int)f2b(o[4]) | ((unsigned int)f2b(o[5]) << 16);
    ov.w = (unsigned int)f2b(o[6]) | ((unsigned int)f2b(o[7]) << 16);
    outb4[(size_t)d * 16 + il] = ov;
  }
}

__global__ __launch_bounds__(256) void k_agg_head_b2(
    const uint4* __restrict__ tpb4, const float* __restrict__ dinv,
    const float* __restrict__ b, const float* __restrict__ Wl,
    const float* __restrict__ bl, const int* __restrict__ rp,
    const int* __restrict__ col, float* __restrict__ out) {
  int wid = threadIdx.x >> 6;
  int lane = threadIdx.x & 63;
  int d = blockIdx.x * 4 + wid;
  int il = lane & 15, g = lane >> 4;

  float acc[8] = {0.f, 0.f, 0.f, 0.f, 0.f, 0.f, 0.f, 0.f};
  int start = rp[d], end = rp[d + 1];
  for (int base = start; base < end; base += 64) {
    int idx = (base + lane < end) ? col[base + lane] : 0;
    int cnt = min(64, end - base);
    for (int it = 0; it < cnt; it += 4) {
      int e = it + g;
      int s = __shfl(idx, e, 64);
      uint4 v = tpb4[(size_t)s * 16 + il];
      acc8(acc, v, (e < cnt) ? 1.f : 0.f);
    }
  }
#pragma unroll
  for (int j = 0; j < 8; ++j) {
    acc[j] += __shfl_xor(acc[j], 16, 64);
    acc[j] += __shfl_xor(acc[j], 32, 64);
  }
  uint4 sv = tpb4[(size_t)d * 16 + il];
  acc8(acc, sv, 1.f);

  float dv = dinv[d];
  float4 b0 = ((const float4*)b)[il * 2];
  float4 b1 = ((const float4*)b)[il * 2 + 1];
  float4 w0 = ((const float4*)Wl)[il * 2];
  float4 w1 = ((const float4*)Wl)[il * 2 + 1];
  float p = 0.f;
  p = fmaf(fmaf(dv, acc[0], b0.x), w0.x, p);
  p = fmaf(fmaf(dv, acc[1], b0.y), w0.y, p);
  p = fmaf(fmaf(dv, acc[2], b0.z), w0.z, p);
  p = fmaf(fmaf(dv, acc[3], b0.w), w0.w, p);
  p = fmaf(fmaf(dv, acc[4], b1.x), w1.x, p);
  p = fmaf(fmaf(dv, acc[5], b1.y), w1.y, p);
  p = fmaf(fmaf(dv, acc[6], b1.z), w1.z, p);
  p = fmaf(fmaf(dv, acc[7], b1.w), w1.w, p);
  // reduce across il within the group (groups already merged)
  p += __shfl_xor(p, 1, 64);
  p += __shfl_xor(p, 2, 64);
  p += __shfl_xor(p, 4, 64);
  p += __shfl_xor(p, 8, 64);
  if (lane == 0) out[d] = 1.f / (1.f + expf(-(p + bl[0])));
}

// ---------------- launch ----------------

extern "C" void kernel_launch(void* const* d_in, const int* in_sizes, int n_in,
                              void* d_out, int out_size, void* d_ws, size_t ws_size,
                              hipStream_t stream) {
  const float* x = (const float*)d_in[0];
  const int* ei = (const int*)d_in[1];   // harness passes integer inputs as int32
  const float* W1 = (const float*)d_in[2];
  const float* b1 = (const float*)d_in[3];
  const float* W2 = (const float*)d_in[4];
  const float* b2 = (const float*)d_in[5];
  const float* Wl = (const float*)d_in[6];
  const float* bl = (const float*)d_in[7];
  float* out = (float*)d_out;

  char* ws = (char*)d_ws;
  size_t off = 0;
  auto alloc = [&](size_t bytes) -> char* {
    char* p = ws + off;
    off = (off + bytes + 255) & ~(size_t)255;
    return p;
  };
  int* deg = (int*)alloc(NN * sizeof(int));
  int* cur = (int*)alloc(NN * sizeof(int));
  float* dinv = (float*)alloc(NN * sizeof(float));
  int* rp = (int*)alloc((NN + 1) * sizeof(int));
  int* bsums = (int*)alloc(256 * sizeof(int));
  int* colidx = (int*)alloc(NE * sizeof(int));
  unsigned short* Xb = (unsigned short*)alloc((size_t)NPAD * DD * 2);
  unsigned short* Wt1 = (unsigned short*)alloc(DD * DD * 2);
  unsigned short* Wt2 = (unsigned short*)alloc(DD * DD * 2);
  unsigned short* tpb = (unsigned short*)alloc((size_t)NPAD * DD * 2);
  unsigned short* h1b = (unsigned short*)alloc((size_t)NPAD * DD * 2);
  (void)ws_size;

  const int NB_N = (NN + 255) / 256;   // 196
  const int NB_E = (NE + 255) / 256;   // 3125
  const int* dst = ei + NE;

  k_zero<<<NB_N, 256, 0, stream>>>(deg, cur, NN);
  k_count<<<NB_E, 256, 0, stream>>>(dst, deg, NE);
  k_dinv<<<NB_N, 256, 0, stream>>>(deg, dinv, NN);
  k_scan1<<<NB_N, 256, 0, stream>>>(deg, rp, bsums, NN);
  k_scan2<<<1, 256, 0, stream>>>(bsums, NB_N);
  k_scan3<<<NB_N, 256, 0, stream>>>(rp, bsums, NN, NE);
  k_scatter<<<NB_E, 256, 0, stream>>>(ei, rp, cur, colidx, NE);

  // prep bf16 operands
  k_xb<<<(NPAD * (DD / 4) + 255) / 256, 256, 0, stream>>>(x, (ushort4*)Xb);
  k_wt<<<(2 * DD * DD + 255) / 256, 256, 0, stream>>>(W1, W2, Wt1, Wt2);

  // layer 1
  k_gemm_mfma<<<NPAD / 64, 256, 0, stream>>>(Xb, Wt1, dinv, tpb);
  k_agg_relu_b2<<<NN / 4, 256, 0, stream>>>((const uint4*)tpb, dinv, b1, rp,
                                            colidx, (uint4*)h1b);
  // layer 2 + head
  k_gemm_mfma<<<NPAD / 64, 256, 0, stream>>>(h1b, Wt2, dinv, tpb);
  k_agg_head_b2<<<NN / 4, 256, 0, stream>>>((const uint4*)tpb, dinv, b2, Wl, bl,
                                            rp, colidx, out);
}